// Round 1
// baseline (15791.702 us; speedup 1.0000x reference)
//
#include <hip/hip_runtime.h>
#include <hip/hip_bf16.h>
#include <math.h>

#define HW 64
#define NPIX 4096
#define NB 16
#define NCH 1792

// ---------------------------------------------------------------------------
// init: zero gap/dct accumulators, compute the separable DCT reduction weights
//   wh[i] = (1/5) * sum_u Bh[u,i],  Bh[u,i] = cos(pi*(2i+1)*u/128)*scale(u)
//   scale(0)=sqrt(1/64)=0.125, else sqrt(2/64)
// ---------------------------------------------------------------------------
__global__ __launch_bounds__(256) void init_kernel(float* __restrict__ gap_sum,
                                                   float* __restrict__ dct_sum,
                                                   float* __restrict__ dctw) {
    int tid = blockIdx.x * 256 + threadIdx.x;
    if (tid < NB * NCH) { gap_sum[tid] = 0.f; dct_sum[tid] = 0.f; }
    if (blockIdx.x == 0 && threadIdx.x < HW) {
        int i = threadIdx.x;
        float s = 0.f;
        for (int u = 0; u < 5; ++u) {
            float scale = (u == 0) ? 0.125f : 0.17677669529663687f;
            s += cosf(3.14159265358979323846f * (2.f * i + 1.f) * u / 128.f) * scale;
        }
        dctw[i] = s * 0.2f;
    }
}

// ---------------------------------------------------------------------------
// Direct conv, KxK, pad K/2, input = [act_in (CIN_ACT ch) ; x-slice (3 ch)],
// fused bias + ReLU + optional store + gap/dct reduction.
// Block: 256 threads -> 32x64 spatial tile x 8 output channels.
// Thread t: col c = t&63, rows r0+4k (r0=t>>6, k=0..7) -> 8 pixels x 8 couts.
// Grid: (H/32, COUT/8, B)
// ---------------------------------------------------------------------------
template <int K, int CIN_ACT, int COUT, bool STORE>
__global__ __launch_bounds__(256) void conv_kernel(
    const float* __restrict__ act_in,      // [B][CIN_ACT][64][64] (or unused)
    const float* __restrict__ x,           // [B][6][64][64]
    int x_coff,                            // 0 or 3
    const float* __restrict__ w,           // [COUT][CIN_ACT+3][K][K]
    const float* __restrict__ bias,        // [COUT]
    float* __restrict__ act_out,           // [B][COUT][64][64] (or unused)
    float* __restrict__ gap_sum,           // [B][1792]
    float* __restrict__ dct_sum,           // [B][1792]
    int chan_base,
    const float* __restrict__ dctw)        // [64]
{
    constexpr int PAD = K / 2;
    constexpr int CIN = CIN_ACT + 3;
    constexpr int TILE_H = 32;
    constexpr int LDS_W = HW + K - 1;
    constexpr int LDS_H = TILE_H + K - 1;
    constexpr int KK = K * K;

    __shared__ float s_in[LDS_H * LDS_W];
    __shared__ float s_w[8 * KK];

    const int tid = threadIdx.x;
    const int h0 = blockIdx.x * TILE_H;
    const int co0 = blockIdx.y * 8;
    const int b = blockIdx.z;

    const int c = tid & 63;
    const int r0 = tid >> 6;

    float acc[8][8];
#pragma unroll
    for (int k = 0; k < 8; ++k)
#pragma unroll
        for (int j = 0; j < 8; ++j) acc[k][j] = 0.f;

    for (int ci = 0; ci < CIN; ++ci) {
        __syncthreads();
        const float* src = (ci < CIN_ACT)
            ? act_in + ((size_t)b * CIN_ACT + ci) * NPIX
            : x + ((size_t)b * 6 + x_coff + (ci - CIN_ACT)) * NPIX;
        // stage haloed input tile (zero-padded)
        for (int idx = tid; idx < LDS_H * LDS_W; idx += 256) {
            int ly = idx / LDS_W;
            int lx = idx - ly * LDS_W;
            int gh = h0 + ly - PAD;
            int gw = lx - PAD;
            float v = 0.f;
            if (gh >= 0 && gh < HW && gw >= 0 && gw < HW) v = src[gh * HW + gw];
            s_in[idx] = v;
        }
        // stage weights for 8 output channels of this input channel
        for (int idx = tid; idx < 8 * KK; idx += 256) {
            int j = idx / KK;
            int t = idx - j * KK;
            s_w[idx] = w[((size_t)(co0 + j) * CIN + ci) * KK + t];
        }
        __syncthreads();

#pragma unroll 1
        for (int ky = 0; ky < K; ++ky) {
            const int row0 = (r0 + ky) * LDS_W + c;
#pragma unroll
            for (int kx = 0; kx < K; ++kx) {
                float wr[8];
#pragma unroll
                for (int j = 0; j < 8; ++j) wr[j] = s_w[j * KK + ky * K + kx];
#pragma unroll
                for (int k = 0; k < 8; ++k) {
                    float iv = s_in[row0 + k * 4 * LDS_W + kx];
#pragma unroll
                    for (int j = 0; j < 8; ++j) acc[k][j] = fmaf(iv, wr[j], acc[k][j]);
                }
            }
        }
    }

    // epilogue: bias + relu (+ store) + per-thread partial reductions
    float bj[8];
#pragma unroll
    for (int j = 0; j < 8; ++j) bj[j] = bias[co0 + j];
    const float wcol = dctw[c];

    float gsum[8], dsum[8];
#pragma unroll
    for (int j = 0; j < 8; ++j) { gsum[j] = 0.f; dsum[j] = 0.f; }

#pragma unroll
    for (int k = 0; k < 8; ++k) {
        const int gh = h0 + r0 + 4 * k;
        const float wrow = dctw[gh];
#pragma unroll
        for (int j = 0; j < 8; ++j) {
            float v = fmaxf(acc[k][j] + bj[j], 0.f);
            if constexpr (STORE)
                act_out[(((size_t)b * COUT + co0 + j) * HW + gh) * HW + c] = v;
            gsum[j] += v;
            dsum[j] = fmaf(v, wrow * wcol, dsum[j]);
        }
    }

    // wave(64)-level reduction, then one atomic per wave per channel
#pragma unroll
    for (int j = 0; j < 8; ++j) {
        float g = gsum[j], d = dsum[j];
#pragma unroll
        for (int off = 32; off > 0; off >>= 1) {
            g += __shfl_down(g, off, 64);
            d += __shfl_down(d, off, 64);
        }
        if ((tid & 63) == 0) {
            const int ch = chan_base + co0 + j;
            atomicAdd(&gap_sum[b * NCH + ch], g);
            atomicAdd(&dct_sum[b * NCH + ch], d);
        }
    }
}

// ---------------------------------------------------------------------------
// head: gap_pred = (gap_sum/4096) @ gap_w^T + gap_b
//       dct_pred = BN(dct_sum)    @ dct_w^T + dct_b
// One block per (b, kind, i): 16*2*12 = 384 blocks.
// ---------------------------------------------------------------------------
__global__ __launch_bounds__(256) void head_kernel(
    const float* __restrict__ gap_sum, const float* __restrict__ dct_sum,
    const float* __restrict__ gap_w, const float* __restrict__ gap_b,
    const float* __restrict__ dct_w, const float* __restrict__ dct_b,
    const float* __restrict__ gamma, const float* __restrict__ beta,
    const float* __restrict__ mean, const float* __restrict__ var,
    float* __restrict__ out)
{
    const int blk = blockIdx.x;
    const int b = blk / 24;
    const int rem = blk - b * 24;
    const int kind = rem / 12;
    const int i = rem - kind * 12;
    const int tid = threadIdx.x;

    float partial = 0.f;
    if (kind == 0) {
        for (int cc = tid; cc < NCH; cc += 256)
            partial += gap_sum[b * NCH + cc] * (1.f / 4096.f) * gap_w[i * NCH + cc];
    } else {
        for (int cc = tid; cc < NCH; cc += 256) {
            float f = dct_sum[b * NCH + cc];
            f = gamma[cc] * (f - mean[cc]) * rsqrtf(var[cc] + 1e-5f) + beta[cc];
            partial += f * dct_w[i * NCH + cc];
        }
    }
#pragma unroll
    for (int off = 32; off > 0; off >>= 1) partial += __shfl_down(partial, off, 64);
    __shared__ float red[4];
    if ((tid & 63) == 0) red[tid >> 6] = partial;
    __syncthreads();
    if (tid == 0) {
        float tot = red[0] + red[1] + red[2] + red[3];
        tot += (kind == 0 ? gap_b[i] : dct_b[i]);
        out[kind * (NB * 12) + b * 12 + i] = tot;
    }
}

// ---------------------------------------------------------------------------
extern "C" void kernel_launch(void* const* d_in, const int* in_sizes, int n_in,
                              void* d_out, int out_size, void* d_ws, size_t ws_size,
                              hipStream_t stream)
{
    const float* x = (const float*)d_in[0];

    float* ws = (float*)d_ws;
    float* dctw    = ws;                         // 64 floats
    float* gap_sum = ws + 64;                    // 16*1792
    float* dct_sum = gap_sum + NB * NCH;         // 16*1792
    float* a3      = dct_sum + NB * NCH;         // 16*64*4096  (16 MB)
    float* a5      = a3 + (size_t)NB * 64 * NPIX; // 16*128*4096 (32 MB)

    hipLaunchKernelGGL(init_kernel, dim3((NB * NCH + 255) / 256), dim3(256), 0, stream,
                       gap_sum, dct_sum, dctw);

    for (int br = 0; br < 4; ++br) {
        const int wi = 1 + br * 6;
        const float* c3w = (const float*)d_in[wi + 0];
        const float* c3b = (const float*)d_in[wi + 1];
        const float* c5w = (const float*)d_in[wi + 2];
        const float* c5b = (const float*)d_in[wi + 3];
        const float* c7w = (const float*)d_in[wi + 4];
        const float* c7b = (const float*)d_in[wi + 5];
        const int coff  = (br / 2) * 3;   // branches 0,1 use x[:, :3]; 2,3 use x[:, 3:]
        const int cbase = br * 448;       // channel base in the 1792-concat

        hipLaunchKernelGGL((conv_kernel<3, 0, 64, true>), dim3(2, 8, NB), dim3(256), 0, stream,
                           (const float*)nullptr, x, coff, c3w, c3b, a3,
                           gap_sum, dct_sum, cbase, dctw);
        hipLaunchKernelGGL((conv_kernel<5, 64, 128, true>), dim3(2, 16, NB), dim3(256), 0, stream,
                           a3, x, coff, c5w, c5b, a5,
                           gap_sum, dct_sum, cbase + 64, dctw);
        hipLaunchKernelGGL((conv_kernel<7, 128, 256, false>), dim3(2, 32, NB), dim3(256), 0, stream,
                           a5, x, coff, c7w, c7b, (float*)nullptr,
                           gap_sum, dct_sum, cbase + 192, dctw);
    }

    hipLaunchKernelGGL(head_kernel, dim3(NB * 24), dim3(256), 0, stream,
                       gap_sum, dct_sum,
                       (const float*)d_in[25], (const float*)d_in[26],
                       (const float*)d_in[27], (const float*)d_in[28],
                       (const float*)d_in[29], (const float*)d_in[30],
                       (const float*)d_in[31], (const float*)d_in[32],
                       (float*)d_out);
}

// Round 2
// 1280.031 us; speedup vs baseline: 12.3370x; 12.3370x over previous
//
#include <hip/hip_runtime.h>
#include <hip/hip_bf16.h>
#include <math.h>

#define HW 64
#define NPIX 4096
#define NB 16
#define NCH 1792

typedef __bf16 bf16;
typedef __bf16 bf16x8 __attribute__((ext_vector_type(8)));
typedef float f32x4 __attribute__((ext_vector_type(4)));

// ---------------------------------------------------------------------------
// init: zero gap/dct accumulators + separable DCT reduction weights
//   dctw[i] = (1/5) * sum_u cos(pi*(2i+1)*u/128)*scale(u)
// ---------------------------------------------------------------------------
__global__ __launch_bounds__(256) void init_kernel(float* __restrict__ gap_sum,
                                                   float* __restrict__ dct_sum,
                                                   float* __restrict__ dctw) {
    int tid = blockIdx.x * 256 + threadIdx.x;
    if (tid < NB * NCH) { gap_sum[tid] = 0.f; dct_sum[tid] = 0.f; }
    if (blockIdx.x == 0 && threadIdx.x < HW) {
        int i = threadIdx.x;
        float s = 0.f;
        for (int u = 0; u < 5; ++u) {
            float scale = (u == 0) ? 0.125f : 0.17677669529663687f;
            s += cosf(3.14159265358979323846f * (2.f * i + 1.f) * u / 128.f) * scale;
        }
        dctw[i] = s * 0.2f;
    }
}

// ---------------------------------------------------------------------------
// x (fp32 NCHW, 6 ch) -> xpad (bf16 NHWC chunks): [B][2][4096][32]
//   group g channels 0..2 = x[b][3g+c], 3..31 = 0
// ---------------------------------------------------------------------------
__global__ __launch_bounds__(256) void prep_x_kernel(const float* __restrict__ x,
                                                     bf16* __restrict__ xpad) {
    int tid = blockIdx.x * 256 + threadIdx.x;   // total NB*2*4096*32 = 2^22
    if (tid >= NB * 2 * NPIX * 32) return;
    int c = tid & 31;
    int pix = (tid >> 5) & (NPIX - 1);
    int g = (tid >> 17) & 1;
    int b = tid >> 18;
    float v = (c < 3) ? x[((size_t)(b * 6 + g * 3 + c)) * NPIX + pix] : 0.f;
    xpad[tid] = (bf16)v;
}

// ---------------------------------------------------------------------------
// weight repack: fp32 [COUT][CIN][K][K] -> bf16 [K*K][CHUNKS][COUT][32]
// channel order: act chunks (32 each) first, last chunk = x(3) + zeros(29)
// ---------------------------------------------------------------------------
template <int K, int CHUNKS, int CIN_ACT, int COUT>
__global__ __launch_bounds__(256) void prep_w_kernel(const float* __restrict__ w,
                                                     bf16* __restrict__ wrep) {
    constexpr int CIN = CIN_ACT + 3;
    const int total = K * K * CHUNKS * COUT * 32;
    int tid = blockIdx.x * 256 + threadIdx.x;
    if (tid >= total) return;
    int cc = tid & 31;
    int co = (tid >> 5) % COUT;
    int rest = tid / (32 * COUT);
    int chunk = rest % CHUNKS;
    int ks = rest / CHUNKS;
    int ky = ks / K, kx = ks % K;
    int ci;
    if (chunk < CHUNKS - 1) ci = chunk * 32 + cc;
    else ci = (cc < 3) ? (CIN_ACT + cc) : -1;
    float v = (ci >= 0) ? w[(((size_t)co * CIN + ci) * K + ky) * K + kx] : 0.f;
    wrep[tid] = (bf16)v;
}

// ---------------------------------------------------------------------------
// Implicit-GEMM conv via MFMA 16x16x32 bf16.
// Block 256 thr = 4 waves (2x2): wave tile M=128 pixels (2 rows) x N=NBLK/2.
// Block tile: 4 rows x 64 cols x NBLK couts. Grid (16, COUT/NBLK, B).
// Per 32-ch chunk: input tile staged in LDS [kseg][row][col][8ch] (one
// barrier pair), then K*K taps; A-frags = conflict-free ds_read_b128,
// B-frags = coalesced register loads from repacked L2-resident weights.
// Epilogue: bias+relu (+bf16 NHWC store) + fused gap/dct reduction.
// ---------------------------------------------------------------------------
template <int K, int CHUNKS, int COUT, int NBLK, bool STORE>
__global__ __launch_bounds__(256, 2) void conv_mfma(
    const bf16* __restrict__ act_in,   // [B][4096][(CHUNKS-1)*32] or null
    const bf16* __restrict__ xpad,     // [B][2][4096][32]
    int g,
    const bf16* __restrict__ wrep,     // [K*K][CHUNKS][COUT][32]
    const float* __restrict__ bias,    // [COUT]
    bf16* __restrict__ act_out,        // [B][4096][COUT] or null
    float* __restrict__ gap_sum, float* __restrict__ dct_sum,
    int chan_base, const float* __restrict__ dctw)
{
    constexpr int PAD = K / 2;
    constexpr int R = 4;
    constexpr int HR = R + K - 1;
    constexpr int WC = HW + K - 1;
    constexpr int ACT_CHUNKS = CHUNKS - 1;
    constexpr int AS = ACT_CHUNKS * 32;          // act channel stride
    constexpr int WN = NBLK / 32;                // n-tiles per wave
    constexpr int NUNITS = 4 * HR * WC;          // 16B units per chunk tile
    constexpr int CW = CHUNKS * COUT * 32;       // wrep elements per tap

    __shared__ __align__(16) bf16 s_in[NUNITS * 8];

    const int tid = threadIdx.x;
    const int lane = tid & 63;
    const int wv = tid >> 6;
    const int wm = wv >> 1;          // 0..1 -> rows [wm*2, wm*2+2)
    const int wn = wv & 1;
    const int q = lane >> 4;         // quad: k-segment (A) / k-segment (B)
    const int ln = lane & 15;

    const int row0 = blockIdx.x * R;
    const int n0g = blockIdx.y * NBLK + wn * (NBLK / 2);
    const int b = blockIdx.z;

    // per-lane A base offsets (bf16 elements) for the wave's 8 m-tiles
    int abase[8];
#pragma unroll
    for (int t = 0; t < 8; ++t) {
        int lr = wm * 2 + (t >> 2);
        int ct = (t & 3) * 16;
        abase[t] = ((q * HR + lr) * WC + ct + ln) * 8;
    }
    const int lane_w = ln * 32 + q * 8;

    f32x4 acc[8][WN];
#pragma unroll
    for (int t = 0; t < 8; ++t)
#pragma unroll
        for (int u = 0; u < WN; ++u) acc[t][u] = f32x4{0.f, 0.f, 0.f, 0.f};

    const bf16* xsrc = xpad + ((size_t)(b * 2 + g)) * NPIX * 32;

#pragma unroll 1
    for (int chunk = 0; chunk < CHUNKS; ++chunk) {
        __syncthreads();   // previous chunk's LDS reads complete
        const bf16* src;
        int stride;
        if (chunk < ACT_CHUNKS) {
            src = act_in + (size_t)b * NPIX * AS + chunk * 32;
            stride = AS;
        } else {
            src = xsrc;
            stride = 32;
        }
        for (int uidx = tid; uidx < NUNITS; uidx += 256) {
            int kseg = uidx / (HR * WC);
            int rem = uidx - kseg * (HR * WC);
            int rr = rem / WC;
            int col = rem - rr * WC;
            int gr = row0 + rr - PAD;
            int gc = col - PAD;
            bf16x8 v;
#pragma unroll
            for (int j = 0; j < 8; ++j) v[j] = (bf16)0.f;
            if (gr >= 0 && gr < HW && gc >= 0 && gc < HW)
                v = *(const bf16x8*)(src + (size_t)(gr * HW + gc) * stride + kseg * 8);
            *(bf16x8*)(s_in + uidx * 8) = v;
        }
        __syncthreads();   // staging visible

        const bf16* wchunk = wrep + ((size_t)chunk * COUT + n0g) * 32 + lane_w;

#pragma unroll 1
        for (int ky = 0; ky < K; ++ky) {
            const bf16* wky = wchunk + (size_t)(ky * K) * CW;
            const int kyoff = ky * WC * 8;
#pragma unroll
            for (int kx = 0; kx < K; ++kx) {
                const int koff = kyoff + kx * 8;
                const bf16* wstep = wky + (size_t)kx * CW;
                bf16x8 bfr[WN];
#pragma unroll
                for (int u = 0; u < WN; ++u)
                    bfr[u] = *(const bf16x8*)(wstep + u * 512);
                bf16x8 afr[8];
#pragma unroll
                for (int t = 0; t < 8; ++t)
                    afr[t] = *(const bf16x8*)(s_in + abase[t] + koff);
#pragma unroll
                for (int t = 0; t < 8; ++t)
#pragma unroll
                    for (int u = 0; u < WN; ++u)
                        acc[t][u] = __builtin_amdgcn_mfma_f32_16x16x32_bf16(
                            afr[t], bfr[u], acc[t][u], 0, 0, 0);
            }
        }
    }

    // ---- epilogue: bias + relu (+store) + gap/dct reduction ----
    float gsum[WN], dsum[WN], bv[WN];
#pragma unroll
    for (int u = 0; u < WN; ++u) {
        gsum[u] = 0.f; dsum[u] = 0.f;
        bv[u] = bias[n0g + u * 16 + ln];
    }

#pragma unroll
    for (int t = 0; t < 8; ++t) {
        const int lr = wm * 2 + (t >> 2);
        const int gr = row0 + lr;
        const float wrow = dctw[gr];
        const int ct = (t & 3) * 16;
#pragma unroll
        for (int r = 0; r < 4; ++r) {
            const int gc = ct + q * 4 + r;          // C/D: row=(lane>>4)*4+reg
            const float wcd = dctw[gc] * wrow;
            const size_t pixoff = ((size_t)b * NPIX + gr * HW + gc) * COUT;
#pragma unroll
            for (int u = 0; u < WN; ++u) {
                float v = fmaxf(acc[t][u][r] + bv[u], 0.f);
                if constexpr (STORE)
                    act_out[pixoff + n0g + u * 16 + ln] = (bf16)v;
                gsum[u] += v;
                dsum[u] = fmaf(v, wcd, dsum[u]);
            }
        }
    }

#pragma unroll
    for (int u = 0; u < WN; ++u) {
        float gv = gsum[u], dv = dsum[u];
        gv += __shfl_xor(gv, 16, 64); gv += __shfl_xor(gv, 32, 64);
        dv += __shfl_xor(dv, 16, 64); dv += __shfl_xor(dv, 32, 64);
        if (q == 0) {
            int ch = chan_base + n0g + u * 16 + ln;
            atomicAdd(&gap_sum[b * NCH + ch], gv);
            atomicAdd(&dct_sum[b * NCH + ch], dv);
        }
    }
}

// ---------------------------------------------------------------------------
// head (unchanged from round 1, verified): gap/BN/dct GEMMs -> 384 outputs
// ---------------------------------------------------------------------------
__global__ __launch_bounds__(256) void head_kernel(
    const float* __restrict__ gap_sum, const float* __restrict__ dct_sum,
    const float* __restrict__ gap_w, const float* __restrict__ gap_b,
    const float* __restrict__ dct_w, const float* __restrict__ dct_b,
    const float* __restrict__ gamma, const float* __restrict__ beta,
    const float* __restrict__ mean, const float* __restrict__ var,
    float* __restrict__ out)
{
    const int blk = blockIdx.x;
    const int b = blk / 24;
    const int rem = blk - b * 24;
    const int kind = rem / 12;
    const int i = rem - kind * 12;
    const int tid = threadIdx.x;

    float partial = 0.f;
    if (kind == 0) {
        for (int cc = tid; cc < NCH; cc += 256)
            partial += gap_sum[b * NCH + cc] * (1.f / 4096.f) * gap_w[i * NCH + cc];
    } else {
        for (int cc = tid; cc < NCH; cc += 256) {
            float f = dct_sum[b * NCH + cc];
            f = gamma[cc] * (f - mean[cc]) * rsqrtf(var[cc] + 1e-5f) + beta[cc];
            partial += f * dct_w[i * NCH + cc];
        }
    }
#pragma unroll
    for (int off = 32; off > 0; off >>= 1) partial += __shfl_down(partial, off, 64);
    __shared__ float red[4];
    if ((tid & 63) == 0) red[tid >> 6] = partial;
    __syncthreads();
    if (tid == 0) {
        float tot = red[0] + red[1] + red[2] + red[3];
        tot += (kind == 0 ? gap_b[i] : dct_b[i]);
        out[kind * (NB * 12) + b * 12 + i] = tot;
    }
}

// ---------------------------------------------------------------------------
extern "C" void kernel_launch(void* const* d_in, const int* in_sizes, int n_in,
                              void* d_out, int out_size, void* d_ws, size_t ws_size,
                              hipStream_t stream)
{
    const float* x = (const float*)d_in[0];

    float* fws = (float*)d_ws;
    float* dctw    = fws;                      // 64
    float* gap_sum = fws + 64;                 // 16*1792
    float* dct_sum = gap_sum + NB * NCH;       // 16*1792
    bf16* bws = (bf16*)(dct_sum + NB * NCH);   // 16B-aligned (229632 B offset)

    bf16* xpad = bws;                                   // 16*2*4096*32 = 4,194,304
    bf16* a3   = xpad + (size_t)NB * 2 * NPIX * 32;     // 16*4096*64  = 4,194,304
    bf16* a5   = a3 + (size_t)NB * NPIX * 64;           // 16*4096*128 = 8,388,608
    bf16* wbase = a5 + (size_t)NB * NPIX * 128;

    const size_t W3SZ = 9 * 1 * 64 * 32;       // 18,432
    const size_t W5SZ = 25 * 3 * 128 * 32;     // 307,200
    const size_t W7SZ = 49 * 5 * 256 * 32;     // 2,007,040
    const size_t WBR  = W3SZ + W5SZ + W7SZ;    // per-branch total

    hipLaunchKernelGGL(init_kernel, dim3((NB * NCH + 255) / 256), dim3(256), 0, stream,
                       gap_sum, dct_sum, dctw);
    hipLaunchKernelGGL(prep_x_kernel, dim3((NB * 2 * NPIX * 32) / 256), dim3(256), 0, stream,
                       x, xpad);

    for (int br = 0; br < 4; ++br) {
        const int wi = 1 + br * 6;
        bf16* w3 = wbase + br * WBR;
        bf16* w5 = w3 + W3SZ;
        bf16* w7 = w5 + W5SZ;
        hipLaunchKernelGGL((prep_w_kernel<3, 1, 0, 64>), dim3((W3SZ + 255) / 256), dim3(256), 0, stream,
                           (const float*)d_in[wi + 0], w3);
        hipLaunchKernelGGL((prep_w_kernel<5, 3, 64, 128>), dim3((W5SZ + 255) / 256), dim3(256), 0, stream,
                           (const float*)d_in[wi + 2], w5);
        hipLaunchKernelGGL((prep_w_kernel<7, 5, 128, 256>), dim3((W7SZ + 255) / 256), dim3(256), 0, stream,
                           (const float*)d_in[wi + 4], w7);
    }

    for (int br = 0; br < 4; ++br) {
        const int wi = 1 + br * 6;
        const int g = br / 2;           // branches 0,1 -> x[:, :3]; 2,3 -> x[:, 3:]
        const int cbase = br * 448;
        bf16* w3 = wbase + br * WBR;
        bf16* w5 = w3 + W3SZ;
        bf16* w7 = w5 + W5SZ;

        hipLaunchKernelGGL((conv_mfma<3, 1, 64, 64, true>), dim3(16, 1, NB), dim3(256), 0, stream,
                           (const bf16*)nullptr, xpad, g, w3, (const float*)d_in[wi + 1],
                           a3, gap_sum, dct_sum, cbase, dctw);
        hipLaunchKernelGGL((conv_mfma<5, 3, 128, 128, true>), dim3(16, 1, NB), dim3(256), 0, stream,
                           a3, xpad, g, w5, (const float*)d_in[wi + 3],
                           a5, gap_sum, dct_sum, cbase + 64, dctw);
        hipLaunchKernelGGL((conv_mfma<7, 5, 256, 128, false>), dim3(16, 2, NB), dim3(256), 0, stream,
                           a5, xpad, g, w7, (const float*)d_in[wi + 5],
                           (bf16*)nullptr, gap_sum, dct_sum, cbase + 192, dctw);
    }

    hipLaunchKernelGGL(head_kernel, dim3(NB * 24), dim3(256), 0, stream,
                       gap_sum, dct_sum,
                       (const float*)d_in[25], (const float*)d_in[26],
                       (const float*)d_in[27], (const float*)d_in[28],
                       (const float*)d_in[29], (const float*)d_in[30],
                       (const float*)d_in[31], (const float*)d_in[32],
                       (float*)d_out);
}

// Round 3
// 1002.200 us; speedup vs baseline: 15.7570x; 1.2772x over previous
//
#include <hip/hip_runtime.h>
#include <hip/hip_bf16.h>
#include <math.h>

#define HW 64
#define NPIX 4096
#define NB 16
#define NCH 1792

typedef __bf16 bf16;
typedef __bf16 bf16x8 __attribute__((ext_vector_type(8)));
typedef float f32x4 __attribute__((ext_vector_type(4)));

struct PtrQuad { const float* p[4]; };

// repacked-weight sizes (bf16 elements), per branch: [w3 | w5 | w7]
constexpr size_t W3SZ = 9 * 1 * 64 * 32;        // 18,432
constexpr size_t W5SZ = 25 * 3 * 128 * 32;      // 307,200
constexpr size_t W7SZ = 49 * 5 * 256 * 32;      // 2,007,040
constexpr size_t WBR  = W3SZ + W5SZ + W7SZ;     // 2,332,672

// ---------------------------------------------------------------------------
// init: zero gap/dct accumulators + separable DCT reduction weights
// ---------------------------------------------------------------------------
__global__ __launch_bounds__(256) void init_kernel(float* __restrict__ gap_sum,
                                                   float* __restrict__ dct_sum,
                                                   float* __restrict__ dctw) {
    int tid = blockIdx.x * 256 + threadIdx.x;
    if (tid < NB * NCH) { gap_sum[tid] = 0.f; dct_sum[tid] = 0.f; }
    if (blockIdx.x == 0 && threadIdx.x < HW) {
        int i = threadIdx.x;
        float s = 0.f;
        for (int u = 0; u < 5; ++u) {
            float scale = (u == 0) ? 0.125f : 0.17677669529663687f;
            s += cosf(3.14159265358979323846f * (2.f * i + 1.f) * u / 128.f) * scale;
        }
        dctw[i] = s * 0.2f;
    }
}

// ---------------------------------------------------------------------------
// x (fp32 NCHW, 6 ch) -> xpad (bf16 NHWC chunks): [B][2][4096][32]
// ---------------------------------------------------------------------------
__global__ __launch_bounds__(256) void prep_x_kernel(const float* __restrict__ x,
                                                     bf16* __restrict__ xpad) {
    int tid = blockIdx.x * 256 + threadIdx.x;
    if (tid >= NB * 2 * NPIX * 32) return;
    int c = tid & 31;
    int pix = (tid >> 5) & (NPIX - 1);
    int g = (tid >> 17) & 1;
    int b = tid >> 18;
    float v = (c < 3) ? x[((size_t)(b * 6 + g * 3 + c)) * NPIX + pix] : 0.f;
    xpad[tid] = (bf16)v;
}

// ---------------------------------------------------------------------------
// weight repack, all 4 branches in one launch:
// fp32 [COUT][CIN][K][K] -> bf16 [K*K][CHUNKS][COUT][32] at dst + br*WBR
// ---------------------------------------------------------------------------
template <int K, int CHUNKS, int CIN_ACT, int COUT>
__global__ __launch_bounds__(256) void prep_w_all(PtrQuad src, bf16* __restrict__ dst) {
    constexpr int CIN = CIN_ACT + 3;
    constexpr int TOT = K * K * CHUNKS * COUT * 32;
    int tid = blockIdx.x * 256 + threadIdx.x;
    if (tid >= 4 * TOT) return;
    int br = tid / TOT;
    int idx = tid - br * TOT;
    int cc = idx & 31;
    int co = (idx >> 5) % COUT;
    int rest = idx / (32 * COUT);
    int chunk = rest % CHUNKS;
    int ks = rest / CHUNKS;
    int ky = ks / K, kx = ks % K;
    int ci;
    if (chunk < CHUNKS - 1) ci = chunk * 32 + cc;
    else ci = (cc < 3) ? (CIN_ACT + cc) : -1;
    const float* w = src.p[br];
    float v = (ci >= 0) ? w[(((size_t)co * CIN + ci) * K + ky) * K + kx] : 0.f;
    dst[(size_t)br * WBR + idx] = (bf16)v;
}

// ---------------------------------------------------------------------------
// Implicit-GEMM conv via MFMA 16x16x32 bf16, ALL branches in one launch.
// Block 256 thr = 4 waves (2x2): wave tile 128 pixels (2 rows) x NBLK/2 couts.
// Grid (16, COUT/NBLK, NB*nbr); blockIdx.z -> (b = z&15, lbr = z>>4).
// LDS input tile [kseg][row][col][8ch], kseg stride padded +1 unit (16B) to
// break the 16-bank quad aliasing seen in round 2.
// ---------------------------------------------------------------------------
template <int K, int CHUNKS, int COUT, int NBLK, bool STORE>
__global__ __launch_bounds__(256, 2) void conv_mfma(
    const bf16* __restrict__ act_in, size_t a_in_brs,   // [lbr][B][4096][AS]
    const bf16* __restrict__ xpad,                      // [B][2][4096][32]
    const bf16* __restrict__ wall, size_t stage_woff,   // wall + br*WBR + off
    PtrQuad biasq,
    bf16* __restrict__ act_out, size_t a_out_brs,       // [lbr][B][4096][COUT]
    float* __restrict__ gap_sum, float* __restrict__ dct_sum,
    int stage_coff, const float* __restrict__ dctw, int br0)
{
    constexpr int PAD = K / 2;
    constexpr int R = 4;
    constexpr int HR = R + K - 1;
    constexpr int WC = HW + K - 1;
    constexpr int ACT_CHUNKS = CHUNKS - 1;
    constexpr int AS = ACT_CHUNKS * 32;
    constexpr int WN = NBLK / 32;
    constexpr int NUNITS = 4 * HR * WC;          // real 16B units per chunk
    constexpr int SEGU = HR * WC + 1;            // padded kseg stride (units)
    constexpr int CW = CHUNKS * COUT * 32;

    __shared__ __align__(16) bf16 s_in[4 * SEGU * 8];

    const int tid = threadIdx.x;
    const int lane = tid & 63;
    const int wv = tid >> 6;
    const int wm = wv >> 1;
    const int wn = wv & 1;
    const int q = lane >> 4;
    const int ln = lane & 15;

    const int bz = blockIdx.z;
    const int b = bz & 15;
    const int lbr = bz >> 4;
    const int br = br0 + lbr;
    const int g = br >> 1;

    const int row0 = blockIdx.x * R;
    const int n0g = blockIdx.y * NBLK + wn * (NBLK / 2);

    const bf16* wrep = wall + (size_t)br * WBR + stage_woff;
    const float* bias = biasq.p[br];

    int abase[8];
#pragma unroll
    for (int t = 0; t < 8; ++t) {
        int lr = wm * 2 + (t >> 2);
        int ct = (t & 3) * 16;
        abase[t] = (q * SEGU + lr * WC + ct + ln) * 8;
    }
    const int lane_w = ln * 32 + q * 8;

    f32x4 acc[8][WN];
#pragma unroll
    for (int t = 0; t < 8; ++t)
#pragma unroll
        for (int u = 0; u < WN; ++u) acc[t][u] = f32x4{0.f, 0.f, 0.f, 0.f};

    const bf16* xsrc = xpad + ((size_t)(b * 2 + g)) * NPIX * 32;
    const bf16* actb = act_in + lbr * a_in_brs + (size_t)b * NPIX * AS;

#pragma unroll 1
    for (int chunk = 0; chunk < CHUNKS; ++chunk) {
        __syncthreads();
        const bf16* src;
        int stride;
        if (chunk < ACT_CHUNKS) { src = actb + chunk * 32; stride = AS; }
        else                    { src = xsrc;              stride = 32; }
        for (int uidx = tid; uidx < NUNITS; uidx += 256) {
            int kseg = uidx / (HR * WC);
            int rem = uidx - kseg * (HR * WC);
            int rr = rem / WC;
            int col = rem - rr * WC;
            int gr = row0 + rr - PAD;
            int gc = col - PAD;
            bf16x8 v;
#pragma unroll
            for (int j = 0; j < 8; ++j) v[j] = (bf16)0.f;
            if (gr >= 0 && gr < HW && gc >= 0 && gc < HW)
                v = *(const bf16x8*)(src + (size_t)(gr * HW + gc) * stride + kseg * 8);
            *(bf16x8*)(s_in + (kseg * SEGU + rem) * 8) = v;
        }
        __syncthreads();

        const bf16* wchunk = wrep + ((size_t)chunk * COUT + n0g) * 32 + lane_w;

#pragma unroll 1
        for (int ky = 0; ky < K; ++ky) {
            const bf16* wky = wchunk + (size_t)(ky * K) * CW;
            const int kyoff = ky * WC * 8;
#pragma unroll
            for (int kx = 0; kx < K; ++kx) {
                const int koff = kyoff + kx * 8;
                const bf16* wstep = wky + (size_t)kx * CW;
                bf16x8 bfr[WN];
#pragma unroll
                for (int u = 0; u < WN; ++u)
                    bfr[u] = *(const bf16x8*)(wstep + u * 512);
                bf16x8 afr[8];
#pragma unroll
                for (int t = 0; t < 8; ++t)
                    afr[t] = *(const bf16x8*)(s_in + abase[t] + koff);
#pragma unroll
                for (int t = 0; t < 8; ++t)
#pragma unroll
                    for (int u = 0; u < WN; ++u)
                        acc[t][u] = __builtin_amdgcn_mfma_f32_16x16x32_bf16(
                            afr[t], bfr[u], acc[t][u], 0, 0, 0);
            }
        }
    }

    // ---- epilogue: bias + relu (+store) + gap/dct reduction ----
    float gsum[WN], dsum[WN], bv[WN];
#pragma unroll
    for (int u = 0; u < WN; ++u) {
        gsum[u] = 0.f; dsum[u] = 0.f;
        bv[u] = bias[n0g + u * 16 + ln];
    }

    bf16* outb = act_out + lbr * a_out_brs;

#pragma unroll
    for (int t = 0; t < 8; ++t) {
        const int lr = wm * 2 + (t >> 2);
        const int gr = row0 + lr;
        const float wrow = dctw[gr];
        const int ct = (t & 3) * 16;
#pragma unroll
        for (int r = 0; r < 4; ++r) {
            const int gc = ct + q * 4 + r;
            const float wcd = dctw[gc] * wrow;
            const size_t pixoff = ((size_t)b * NPIX + gr * HW + gc) * COUT;
#pragma unroll
            for (int u = 0; u < WN; ++u) {
                float v = fmaxf(acc[t][u][r] + bv[u], 0.f);
                if constexpr (STORE)
                    outb[pixoff + n0g + u * 16 + ln] = (bf16)v;
                gsum[u] += v;
                dsum[u] = fmaf(v, wcd, dsum[u]);
            }
        }
    }

    const int chan_base = br * 448 + stage_coff;
#pragma unroll
    for (int u = 0; u < WN; ++u) {
        float gv = gsum[u], dv = dsum[u];
        gv += __shfl_xor(gv, 16, 64); gv += __shfl_xor(gv, 32, 64);
        dv += __shfl_xor(dv, 16, 64); dv += __shfl_xor(dv, 32, 64);
        if (q == 0) {
            int ch = chan_base + n0g + u * 16 + ln;
            atomicAdd(&gap_sum[b * NCH + ch], gv);
            atomicAdd(&dct_sum[b * NCH + ch], dv);
        }
    }
}

// ---------------------------------------------------------------------------
// head: gap/BN/dct GEMMs -> 384 outputs (verified rounds 1-2)
// ---------------------------------------------------------------------------
__global__ __launch_bounds__(256) void head_kernel(
    const float* __restrict__ gap_sum, const float* __restrict__ dct_sum,
    const float* __restrict__ gap_w, const float* __restrict__ gap_b,
    const float* __restrict__ dct_w, const float* __restrict__ dct_b,
    const float* __restrict__ gamma, const float* __restrict__ beta,
    const float* __restrict__ mean, const float* __restrict__ var,
    float* __restrict__ out)
{
    const int blk = blockIdx.x;
    const int b = blk / 24;
    const int rem = blk - b * 24;
    const int kind = rem / 12;
    const int i = rem - kind * 12;
    const int tid = threadIdx.x;

    float partial = 0.f;
    if (kind == 0) {
        for (int cc = tid; cc < NCH; cc += 256)
            partial += gap_sum[b * NCH + cc] * (1.f / 4096.f) * gap_w[i * NCH + cc];
    } else {
        for (int cc = tid; cc < NCH; cc += 256) {
            float f = dct_sum[b * NCH + cc];
            f = gamma[cc] * (f - mean[cc]) * rsqrtf(var[cc] + 1e-5f) + beta[cc];
            partial += f * dct_w[i * NCH + cc];
        }
    }
#pragma unroll
    for (int off = 32; off > 0; off >>= 1) partial += __shfl_down(partial, off, 64);
    __shared__ float red[4];
    if ((tid & 63) == 0) red[tid >> 6] = partial;
    __syncthreads();
    if (tid == 0) {
        float tot = red[0] + red[1] + red[2] + red[3];
        tot += (kind == 0 ? gap_b[i] : dct_b[i]);
        out[kind * (NB * 12) + b * 12 + i] = tot;
    }
}

// ---------------------------------------------------------------------------
extern "C" void kernel_launch(void* const* d_in, const int* in_sizes, int n_in,
                              void* d_out, int out_size, void* d_ws, size_t ws_size,
                              hipStream_t stream)
{
    const float* x = (const float*)d_in[0];

    float* fws = (float*)d_ws;
    float* dctw    = fws;                      // 64
    float* gap_sum = fws + 64;                 // 16*1792
    float* dct_sum = gap_sum + NB * NCH;       // 16*1792
    bf16* bws = (bf16*)(dct_sum + NB * NCH);

    const size_t XPSZ = (size_t)NB * 2 * NPIX * 32;   // 4,194,304
    const size_t A3B  = (size_t)NB * NPIX * 64;       // 4,194,304
    const size_t A5B  = (size_t)NB * NPIX * 128;      // 8,388,608

    // choose how many branches per conv launch based on available scratch
    const size_t fixed = 229632 + 2 * (XPSZ + 4 * WBR);
    int nbr = 1;
    if (ws_size >= fixed + 2 * 4 * (A3B + A5B)) nbr = 4;
    else if (ws_size >= fixed + 2 * 2 * (A3B + A5B)) nbr = 2;

    bf16* xpad = bws;
    bf16* wall = xpad + XPSZ;
    bf16* a3   = wall + 4 * WBR;
    bf16* a5   = a3 + (size_t)nbr * A3B;

    hipLaunchKernelGGL(init_kernel, dim3((NB * NCH + 255) / 256), dim3(256), 0, stream,
                       gap_sum, dct_sum, dctw);
    hipLaunchKernelGGL(prep_x_kernel, dim3((NB * 2 * NPIX * 32) / 256), dim3(256), 0, stream,
                       x, xpad);

    PtrQuad w3q = {{(const float*)d_in[1], (const float*)d_in[7], (const float*)d_in[13], (const float*)d_in[19]}};
    PtrQuad b3q = {{(const float*)d_in[2], (const float*)d_in[8], (const float*)d_in[14], (const float*)d_in[20]}};
    PtrQuad w5q = {{(const float*)d_in[3], (const float*)d_in[9], (const float*)d_in[15], (const float*)d_in[21]}};
    PtrQuad b5q = {{(const float*)d_in[4], (const float*)d_in[10], (const float*)d_in[16], (const float*)d_in[22]}};
    PtrQuad w7q = {{(const float*)d_in[5], (const float*)d_in[11], (const float*)d_in[17], (const float*)d_in[23]}};
    PtrQuad b7q = {{(const float*)d_in[6], (const float*)d_in[12], (const float*)d_in[18], (const float*)d_in[24]}};

    hipLaunchKernelGGL((prep_w_all<3, 1, 0, 64>), dim3((4 * W3SZ + 255) / 256), dim3(256), 0, stream,
                       w3q, wall);
    hipLaunchKernelGGL((prep_w_all<5, 3, 64, 128>), dim3((4 * W5SZ + 255) / 256), dim3(256), 0, stream,
                       w5q, wall + W3SZ);
    hipLaunchKernelGGL((prep_w_all<7, 5, 128, 256>), dim3((4 * W7SZ + 255) / 256), dim3(256), 0, stream,
                       w7q, wall + W3SZ + W5SZ);

    for (int br0 = 0; br0 < 4; br0 += nbr) {
        hipLaunchKernelGGL((conv_mfma<3, 1, 64, 64, true>), dim3(16, 1, NB * nbr), dim3(256), 0, stream,
                           (const bf16*)nullptr, 0, xpad, wall, 0, b3q,
                           a3, A3B, gap_sum, dct_sum, 0, dctw, br0);
        hipLaunchKernelGGL((conv_mfma<5, 3, 128, 128, true>), dim3(16, 1, NB * nbr), dim3(256), 0, stream,
                           a3, A3B, xpad, wall, W3SZ, b5q,
                           a5, A5B, gap_sum, dct_sum, 64, dctw, br0);
        hipLaunchKernelGGL((conv_mfma<7, 5, 256, 128, false>), dim3(16, 2, NB * nbr), dim3(256), 0, stream,
                           a5, A5B, xpad, wall, W3SZ + W5SZ, b7q,
                           (bf16*)nullptr, 0, gap_sum, dct_sum, 192, dctw, br0);
    }

    hipLaunchKernelGGL(head_kernel, dim3(NB * 24), dim3(256), 0, stream,
                       gap_sum, dct_sum,
                       (const float*)d_in[25], (const float*)d_in[26],
                       (const float*)d_in[27], (const float*)d_in[28],
                       (const float*)d_in[29], (const float*)d_in[30],
                       (const float*)d_in[31], (const float*)d_in[32],
                       (float*)d_out);
}